// Round 13
// baseline (136.888 us; speedup 1.0000x reference)
//
#include <hip/hip_runtime.h>
#include <math.h>

#define NSAMP 8
#define CH 64
#define HH 64
#define WW 64
#define SPATIAL 4096        // HH*WW
#define PER_SAMPLE 262144   // CH*SPATIAL
#define NTOK 32768          // NSAMP*SPATIAL
#define NHEADS 4
#define HD 16
#define KS 7
#define EPS 1e-5f
#define QSCALE 0.25f        // HD^-0.5

typedef __attribute__((ext_vector_type(8))) short short8;
typedef __attribute__((ext_vector_type(4))) float f32x4;

__device__ __forceinline__ unsigned short f2bf(float f) {
    unsigned u = __float_as_uint(f);
    u = u + 0x7fffu + ((u >> 16) & 1u);     // round-to-nearest-even
    return (unsigned short)(u >> 16);
}
__device__ __forceinline__ unsigned pack2(float a, float b) {
    return (unsigned)f2bf(a) | ((unsigned)f2bf(b) << 16);
}
__device__ __forceinline__ float dot8_bf(uint4 u, const float* qv) {
    float s;
    s = __uint_as_float(u.x << 16) * qv[0];
    s = fmaf(__uint_as_float(u.x & 0xffff0000u), qv[1], s);
    s = fmaf(__uint_as_float(u.y << 16),         qv[2], s);
    s = fmaf(__uint_as_float(u.y & 0xffff0000u), qv[3], s);
    s = fmaf(__uint_as_float(u.z << 16),         qv[4], s);
    s = fmaf(__uint_as_float(u.z & 0xffff0000u), qv[5], s);
    s = fmaf(__uint_as_float(u.w << 16),         qv[6], s);
    s = fmaf(__uint_as_float(u.w & 0xffff0000u), qv[7], s);
    return s;
}
__device__ __forceinline__ void pv8_bf(uint4 u, float p, float* acc) {
    acc[0] = fmaf(p, __uint_as_float(u.x << 16),         acc[0]);
    acc[1] = fmaf(p, __uint_as_float(u.x & 0xffff0000u), acc[1]);
    acc[2] = fmaf(p, __uint_as_float(u.y << 16),         acc[2]);
    acc[3] = fmaf(p, __uint_as_float(u.y & 0xffff0000u), acc[3]);
    acc[4] = fmaf(p, __uint_as_float(u.z << 16),         acc[4]);
    acc[5] = fmaf(p, __uint_as_float(u.z & 0xffff0000u), acc[5]);
    acc[6] = fmaf(p, __uint_as_float(u.w << 16),         acc[6]);
    acc[7] = fmaf(p, __uint_as_float(u.w & 0xffff0000u), acc[7]);
}

// ---------------- K1: per-sample sum/sumsq (blocks 0-255) + weight->bf16 (blocks 256-447) ----------------
__global__ __launch_bounds__(256) void k_statsprep(const float* __restrict__ x,
                                                   float* __restrict__ stats,
                                                   const float* __restrict__ qkv_w,
                                                   const float* __restrict__ fc1_w,
                                                   const float* __restrict__ fc2_w,
                                                   const float* __restrict__ proj_w,
                                                   unsigned short* __restrict__ wb) {
    int blk = blockIdx.x;
    if (blk >= 256) {           // prep: 192 blocks x 256 = 49152 weights
        int i = (blk - 256) * 256 + threadIdx.x;
        if (i < 12288)      wb[i] = f2bf(qkv_w[i]);
        else if (i < 28672) wb[i] = f2bf(fc1_w[i - 12288]);
        else if (i < 45056) wb[i] = f2bf(fc2_w[i - 28672]);
        else                wb[i] = f2bf(proj_w[i - 45056]);
        return;
    }
    int n = blk >> 5, chunk = blk & 31;
    const float4* p4 = (const float4*)(x + n * PER_SAMPLE + chunk * 8192);
    int t = threadIdx.x;
    float s1 = 0.f, s2 = 0.f;
#pragma unroll
    for (int i = 0; i < 8; i++) {
        float4 v = p4[t + i * 256];
        s1 += v.x + v.y + v.z + v.w;
        s2 += v.x * v.x + v.y * v.y + v.z * v.z + v.w * v.w;
    }
#pragma unroll
    for (int off = 1; off < 64; off <<= 1) {
        s1 += __shfl_xor(s1, off);
        s2 += __shfl_xor(s2, off);
    }
    __shared__ float r1[4], r2[4];
    int lane = t & 63, wv = t >> 6;
    if (lane == 0) { r1[wv] = s1; r2[wv] = s2; }
    __syncthreads();
    if (t == 0) {
        atomicAdd(&stats[n * 2 + 0], r1[0] + r1[1] + r1[2] + r1[3]);
        atomicAdd(&stats[n * 2 + 1], r2[0] + r2[1] + r2[2] + r2[3]);
    }
}

// ---------------- K2: GN + QKV MFMA, block = 32 tokens (half-row), XCD-banded ----------------
__global__ __launch_bounds__(256) void k_qkv(const float* __restrict__ x,
                                             const float* __restrict__ stats,
                                             const float* __restrict__ gn_w,
                                             const float* __restrict__ gn_b,
                                             const unsigned short* __restrict__ qkv_wb,
                                             const float* __restrict__ qkv_b,
                                             uint4* __restrict__ qb8,
                                             uint4* __restrict__ kvb8) {
    __shared__ __attribute__((aligned(16))) short fragA[2 * 2 * 64 * 8];  // 4 KB (M=32 A-frags)
    __shared__ float obuf[4][16 * 33];                                    // 8.25 KB per-wave transpose
    int xcd = blockIdx.x & 7, idx = blockIdx.x >> 3;
    int half = idx & 1;
    int h = xcd * 8 + ((idx >> 1) & 7);
    int n = idx >> 4;
    int t = threadIdx.x, lane = t & 63;
    int g = __builtin_amdgcn_readfirstlane(t >> 6);
    int s0 = n * 4096 + h * 64 + half * 32;
    int nh = lane & 15, qd = lane >> 4;

    float mu = stats[2 * n] * (1.f / (float)PER_SAMPLE);
    float var = stats[2 * n + 1] * (1.f / (float)PER_SAMPLE) - mu * mu;
    float rstd = rsqrtf(var + EPS);

    // stage A: thread owns 8 channels (cbq*8..+7) of token tok32
    {
        int tok32 = t & 31, cbq = t >> 5;
        const float* xp = x + n * PER_SAMPLE + h * 64 + half * 32 + tok32;
        float v[8];
#pragma unroll
        for (int i = 0; i < 8; i++) {
            int c = cbq * 8 + i;
            v[i] = (xp[(size_t)c * SPATIAL] - mu) * rstd * gn_w[c] + gn_b[c];
        }
        int kf = cbq >> 2, qsel = cbq & 3;
        uint4 p;
        p.x = pack2(v[0], v[1]);
        p.y = pack2(v[2], v[3]);
        p.z = pack2(v[4], v[5]);
        p.w = pack2(v[6], v[7]);
        *(uint4*)&fragA[(((tok32 >> 4) * 2 + kf) * 64 + (tok32 & 15) + (qsel << 4)) * 8] = p;
    }
    __syncthreads();

    short8 af[4];
#pragma unroll
    for (int mt = 0; mt < 2; mt++)
#pragma unroll
        for (int kf = 0; kf < 2; kf++)
            af[mt * 2 + kf] = *(const short8*)&fragA[((mt * 2 + kf) * 64 + lane) * 8];

    for (int nt = 0; nt < 3; nt++) {
        int n0 = g * 48 + nt * 16;
        const unsigned short* wp = qkv_wb + (size_t)(n0 + nh) * 64 + qd * 8;
        short8 b0 = *(const short8*)(wp);
        short8 b1 = *(const short8*)(wp + 32);
        float bias = qkv_b[n0 + nh];
        bool isq = (n0 < 64);
#pragma unroll
        for (int mt = 0; mt < 2; mt++) {
            f32x4 d = {0.f, 0.f, 0.f, 0.f};
            d = __builtin_amdgcn_mfma_f32_16x16x32_bf16(af[mt * 2 + 0], b0, d, 0, 0, 0);
            d = __builtin_amdgcn_mfma_f32_16x16x32_bf16(af[mt * 2 + 1], b1, d, 0, 0, 0);
#pragma unroll
            for (int r = 0; r < 4; r++) {
                float vv = d[r] + bias;
                if (isq) vv *= QSCALE;
                obuf[g][nh * 33 + mt * 16 + qd * 4 + r] = vv;
            }
        }
        __builtin_amdgcn_wave_barrier();
        {
            int tok = lane & 31, u = lane >> 5;
            uint4 p;
            p.x = pack2(obuf[g][(u * 8 + 0) * 33 + tok], obuf[g][(u * 8 + 1) * 33 + tok]);
            p.y = pack2(obuf[g][(u * 8 + 2) * 33 + tok], obuf[g][(u * 8 + 3) * 33 + tok]);
            p.z = pack2(obuf[g][(u * 8 + 4) * 33 + tok], obuf[g][(u * 8 + 5) * 33 + tok]);
            p.w = pack2(obuf[g][(u * 8 + 6) * 33 + tok], obuf[g][(u * 8 + 7) * 33 + tok]);
            int row = (n0 >> 3) + u;
            if (n0 < 64) qb8[(size_t)row * NTOK + s0 + tok] = p;        // q rows 0..7
            else         kvb8[(size_t)(row - 8) * NTOK + s0 + tok] = p;  // k 0..7, v 8..15
        }
        __builtin_amdgcn_wave_barrier();
    }
}

// ---------------- K3: attention + proj + LN + MLP, fused; block = 4x8 spatial tile ----------------
// 1024 blocks x 256 threads (4 waves); wave = head; lane = token(0..31) x dim-half(0..1).
// Token = (r,cseg) in a 4-row x 8-col tile: K/V gather window is 10x14 = 140 tokens
// (18 KB unique for 4 heads) -> fits L1, so the 7x per-wave re-reads become L1 hits.
// XCD band (rows xcd*8..+7) matches k_qkv's producer band.
__global__ __launch_bounds__(256, 4) void k_fused(const uint4* __restrict__ qb8,
                                               const uint4* __restrict__ kvb8,
                                               const float* __restrict__ rpb,
                                               const unsigned short* __restrict__ proj_wb,
                                               const float* __restrict__ proj_b,
                                               const float* __restrict__ x,
                                               const float* __restrict__ ln_w,
                                               const float* __restrict__ ln_b,
                                               const unsigned short* __restrict__ fc1_wb,
                                               const float* __restrict__ fc1_b,
                                               const unsigned short* __restrict__ fc2_wb,
                                               const float* __restrict__ fc2_b,
                                               float* __restrict__ out) {
    __shared__ __attribute__((aligned(16))) short fragA[2 * 2 * 64 * 8];  // 4 KB (attn-out, then yn)
    __shared__ __attribute__((aligned(16))) short lhA[2 * 8 * 64 * 8];    // 16 KB (full hidden, M=32)
    __shared__ float obuf[4][16 * 33];                                    // 8.25 KB per-wave transpose
    __shared__ float red1[256], red2[256];                                // 2 KB
    int xcd = blockIdx.x & 7, idx = blockIdx.x >> 3;
    int tr = idx & 1;                   // tile-row within the XCD's 8-row band
    int tc = (idx >> 1) & 7;            // tile-col
    int n = idx >> 4;
    int h0 = xcd * 8 + tr * 4, c0 = tc * 8;
    int t = threadIdx.x, lane = t & 63;
    int g = __builtin_amdgcn_readfirstlane(t >> 6);   // head / wave
    int w2 = lane & 31;                 // token id within tile
    int dh = lane >> 5;                 // dim-half (8 channels each)
    int r = w2 >> 3, cseg = w2 & 7;
    int h = h0 + r, w = c0 + cseg;      // spatial position (per-lane)
    int tok = n * 4096 + h * 64 + w;
    int cb = 2 * g + dh;                // 8-channel block id within 64 channels

    // prefetch x residual: 8 channels c = cb*8 + i (32B-coalesced segments)
    const float* xr = x + n * PER_SAMPLE + h * 64 + w;
    float xres[8];
#pragma unroll
    for (int i = 0; i < 8; i++)
        xres[i] = xr[(size_t)(cb * 8 + i) * SPATIAL];

    // ---- neighborhood attention, one-pass streaming softmax ----
    float q[8];
    {
        uint4 qa = qb8[(size_t)cb * NTOK + tok];
        q[0] = __uint_as_float(qa.x << 16); q[1] = __uint_as_float(qa.x & 0xffff0000u);
        q[2] = __uint_as_float(qa.y << 16); q[3] = __uint_as_float(qa.y & 0xffff0000u);
        q[4] = __uint_as_float(qa.z << 16); q[5] = __uint_as_float(qa.z & 0xffff0000u);
        q[6] = __uint_as_float(qa.w << 16); q[7] = __uint_as_float(qa.w & 0xffff0000u);
    }
    int sh = min(max(h - 3, 0), HH - KS);
    int sw = min(max(w - 3, 0), WW - KS);

    float sum = 0.f;
    float acc[8];
#pragma unroll
    for (int i = 0; i < 8; i++) acc[i] = 0.f;

#pragma unroll
    for (int a = 0; a < 7; a++) {
        int nb = n * 4096 + (sh + a) * 64 + sw;
        const float* rp = rpb + (g * 13 + (h - sh + 6 - a)) * 13 + (w - sw + 6);
        const uint4* kp = kvb8 + (size_t)cb * NTOK + nb;
        const uint4* vp = kvb8 + (size_t)(8 + cb) * NTOK + nb;
#pragma unroll
        for (int bb = 0; bb < 7; bb++) {
            uint4 kv = kp[bb];
            uint4 vv = vp[bb];
            float dhalf = dot8_bf(kv, q);
            float d = dhalf + __shfl_xor(dhalf, 32);   // combine dim-halves
            d += rp[-bb];
            float e = __expf(d);                        // no-max softmax: logits tiny
            sum += e;
            pv8_bf(vv, e, acc);
        }
    }
    float rs = 1.f / sum;

    // stage attn-out (x rs) as bf16 A-frags (M=32, K=64): m=w2, k=cb*8+i
    {
        int kf = cb >> 2, qsel = cb & 3;
        uint4 p;
        p.x = pack2(acc[0] * rs, acc[1] * rs);
        p.y = pack2(acc[2] * rs, acc[3] * rs);
        p.z = pack2(acc[4] * rs, acc[5] * rs);
        p.w = pack2(acc[6] * rs, acc[7] * rs);
        *(uint4*)&fragA[(((w2 >> 4) * 2 + kf) * 64 + (w2 & 15) + (qsel << 4)) * 8] = p;
    }
    __syncthreads();                                    // B1

    int nh = lane & 15, qd = lane >> 4;
    float yreg[8];                                      // y = proj(attn)+bias+x
    // ---- proj MFMA (M=32, N=16/wave, K=64) ----
    {
        short8 af[4];
#pragma unroll
        for (int mt = 0; mt < 2; mt++)
#pragma unroll
            for (int kf = 0; kf < 2; kf++)
                af[mt * 2 + kf] = *(const short8*)&fragA[((mt * 2 + kf) * 64 + lane) * 8];

        int n0 = g * 16;
        const unsigned short* wp = proj_wb + (size_t)(n0 + nh) * 64 + qd * 8;
        short8 b0 = *(const short8*)(wp);
        short8 b1 = *(const short8*)(wp + 32);
        float bias = proj_b[n0 + nh];
#pragma unroll
        for (int mt = 0; mt < 2; mt++) {
            f32x4 d = {0.f, 0.f, 0.f, 0.f};
            d = __builtin_amdgcn_mfma_f32_16x16x32_bf16(af[mt * 2 + 0], b0, d, 0, 0, 0);
            d = __builtin_amdgcn_mfma_f32_16x16x32_bf16(af[mt * 2 + 1], b1, d, 0, 0, 0);
#pragma unroll
            for (int r2 = 0; r2 < 4; r2++)
                obuf[g][nh * 33 + mt * 16 + qd * 4 + r2] = d[r2] + bias;
        }
        __builtin_amdgcn_wave_barrier();
#pragma unroll
        for (int i = 0; i < 8; i++)
            yreg[i] = obuf[g][(dh * 8 + i) * 33 + w2] + xres[i];
    }

    // ---- LN (8 threads per token) -> fragA (yn A-frags) ----
    {
        float s1 = 0.f, s2 = 0.f;
#pragma unroll
        for (int i = 0; i < 8; i++) { s1 += yreg[i]; s2 += yreg[i] * yreg[i]; }
        red1[t] = s1;
        red2[t] = s2;
        __syncthreads();                                // B2 (also orders fragA reuse)
        float m1 = 0.f, m2 = 0.f;
#pragma unroll
        for (int u = 0; u < 8; u++) { m1 += red1[u * 32 + w2]; m2 += red2[u * 32 + w2]; }
        float mu = m1 * (1.f / 64.f);
        float rstd = rsqrtf(m2 * (1.f / 64.f) - mu * mu + EPS);
        float v[8];
#pragma unroll
        for (int i = 0; i < 8; i++) {
            int c = cb * 8 + i;
            v[i] = (yreg[i] - mu) * rstd * ln_w[c] + ln_b[c];
        }
        int kf = cb >> 2, qsel = cb & 3;
        uint4 p;
        p.x = pack2(v[0], v[1]);
        p.y = pack2(v[2], v[3]);
        p.z = pack2(v[4], v[5]);
        p.w = pack2(v[6], v[7]);
        *(uint4*)&fragA[(((w2 >> 4) * 2 + kf) * 64 + (w2 & 15) + (qsel << 4)) * 8] = p;
    }
    __syncthreads();                                    // B3

    // ---- fc1 + GELU -> lhA (fc2 A-frag layout, M=32, K=256) ----
    {
        short8 yf[4];
#pragma unroll
        for (int mt = 0; mt < 2; mt++)
#pragma unroll
            for (int kf = 0; kf < 2; kf++)
                yf[mt * 2 + kf] = *(const short8*)&fragA[((mt * 2 + kf) * 64 + lane) * 8];

#pragma unroll
        for (int nt = 0; nt < 4; nt++) {
            int n0f = g * 64 + nt * 16;
            const unsigned short* wp = fc1_wb + (size_t)(n0f + nh) * 64 + qd * 8;
            short8 b0 = *(const short8*)(wp);
            short8 b1 = *(const short8*)(wp + 32);
            float bias = fc1_b[n0f + nh];
            int j = n0f + nh;
            int kfA = j >> 5, q2 = (j >> 3) & 3, jb = j & 7;
#pragma unroll
            for (int mt = 0; mt < 2; mt++) {
                f32x4 d = {0.f, 0.f, 0.f, 0.f};
                d = __builtin_amdgcn_mfma_f32_16x16x32_bf16(yf[mt * 2 + 0], b0, d, 0, 0, 0);
                d = __builtin_amdgcn_mfma_f32_16x16x32_bf16(yf[mt * 2 + 1], b1, d, 0, 0, 0);
#pragma unroll
                for (int r2 = 0; r2 < 4; r2++) {
                    float hv = d[r2] + bias;
                    hv = 0.5f * hv * (1.f + erff(hv * 0.70710678118654752f));
                    lhA[((mt * 8 + kfA) * 64 + (qd * 4 + r2) + (q2 << 4)) * 8 + jb] = (short)f2bf(hv);
                }
            }
        }
    }
    __syncthreads();                                    // B4

    // ---- fc2 (M=32, N=16/wave, K=256 in one pass) ----
    f32x4 acc2[2];
    acc2[0] = (f32x4){0.f, 0.f, 0.f, 0.f};
    acc2[1] = (f32x4){0.f, 0.f, 0.f, 0.f};
#pragma unroll
    for (int kfA = 0; kfA < 8; kfA++) {
        const unsigned short* wp = fc2_wb + (size_t)(g * 16 + nh) * 256 + kfA * 32 + qd * 8;
        short8 bb = *(const short8*)(wp);
#pragma unroll
        for (int mt = 0; mt < 2; mt++) {
            short8 a = *(const short8*)&lhA[((mt * 8 + kfA) * 64 + lane) * 8];
            acc2[mt] = __builtin_amdgcn_mfma_f32_16x16x32_bf16(a, bb, acc2[mt], 0, 0, 0);
        }
    }
    // ---- epilogue: per-wave transpose, + fc2_b + y residual, NCHW store ----
#pragma unroll
    for (int mt = 0; mt < 2; mt++)
#pragma unroll
        for (int r2 = 0; r2 < 4; r2++)
            obuf[g][nh * 33 + mt * 16 + qd * 4 + r2] = acc2[mt][r2];
    __builtin_amdgcn_wave_barrier();
    float* op = out + (size_t)n * PER_SAMPLE + h * 64 + w;
#pragma unroll
    for (int i = 0; i < 8; i++) {
        int c = cb * 8 + i;
        op[(size_t)c * SPATIAL] = obuf[g][(dh * 8 + i) * 33 + w2] + fc2_b[c] + yreg[i];
    }
}

extern "C" void kernel_launch(void* const* d_in, const int* in_sizes, int n_in,
                              void* d_out, int out_size, void* d_ws, size_t ws_size,
                              hipStream_t stream) {
    const float* x      = (const float*)d_in[0];
    const float* gn_w   = (const float*)d_in[1];
    const float* gn_b   = (const float*)d_in[2];
    const float* qkv_w  = (const float*)d_in[3];
    const float* qkv_b  = (const float*)d_in[4];
    const float* rpb    = (const float*)d_in[5];
    const float* proj_w = (const float*)d_in[6];
    const float* proj_b = (const float*)d_in[7];
    const float* ln_w   = (const float*)d_in[8];
    const float* ln_b   = (const float*)d_in[9];
    const float* fc1_w  = (const float*)d_in[10];
    const float* fc1_b  = (const float*)d_in[11];
    const float* fc2_w  = (const float*)d_in[12];
    const float* fc2_b  = (const float*)d_in[13];
    float* out = (float*)d_out;

    float* ws    = (float*)d_ws;
    float* stats = ws;                                      // 64 floats
    uint4* qb8   = (uint4*)(ws + 64);                       // 8  * NTOK uint4 = 4.2 MB
    uint4* kvb8  = qb8 + (size_t)8 * NTOK;                  // 16 * NTOK uint4 = 8.4 MB
    unsigned short* wb = (unsigned short*)(kvb8 + (size_t)16 * NTOK);  // 49152 bf16
    unsigned short* qkv_wb  = wb;
    unsigned short* fc1_wb  = wb + 12288;
    unsigned short* fc2_wb  = wb + 28672;
    unsigned short* proj_wb = wb + 45056;

    hipMemsetAsync(stats, 0, 64, stream);
    k_statsprep<<<448, 256, 0, stream>>>(x, stats, qkv_w, fc1_w, fc2_w, proj_w, wb);
    k_qkv      <<<1024, 256, 0, stream>>>(x, stats, gn_w, gn_b, qkv_wb, qkv_b, qb8, kvb8);
    k_fused    <<<1024, 256, 0, stream>>>(qb8, kvb8, rpb, proj_wb, proj_b, x,
                                          ln_w, ln_b, fc1_wb, fc1_b, fc2_wb, fc2_b, out);
}

// Round 14
// 130.229 us; speedup vs baseline: 1.0511x; 1.0511x over previous
//
#include <hip/hip_runtime.h>
#include <math.h>

#define NSAMP 8
#define CH 64
#define HH 64
#define WW 64
#define SPATIAL 4096        // HH*WW
#define PER_SAMPLE 262144   // CH*SPATIAL
#define NTOK 32768          // NSAMP*SPATIAL
#define NHEADS 4
#define HD 16
#define KS 7
#define EPS 1e-5f
#define QSCALE 0.25f        // HD^-0.5

typedef __attribute__((ext_vector_type(8))) short short8;
typedef __attribute__((ext_vector_type(4))) float f32x4;

__device__ __forceinline__ unsigned short f2bf(float f) {
    unsigned u = __float_as_uint(f);
    u = u + 0x7fffu + ((u >> 16) & 1u);     // round-to-nearest-even
    return (unsigned short)(u >> 16);
}
__device__ __forceinline__ unsigned pack2(float a, float b) {
    return (unsigned)f2bf(a) | ((unsigned)f2bf(b) << 16);
}
__device__ __forceinline__ float dot8_bf(uint4 u, const float* qv) {
    float s;
    s = __uint_as_float(u.x << 16) * qv[0];
    s = fmaf(__uint_as_float(u.x & 0xffff0000u), qv[1], s);
    s = fmaf(__uint_as_float(u.y << 16),         qv[2], s);
    s = fmaf(__uint_as_float(u.y & 0xffff0000u), qv[3], s);
    s = fmaf(__uint_as_float(u.z << 16),         qv[4], s);
    s = fmaf(__uint_as_float(u.z & 0xffff0000u), qv[5], s);
    s = fmaf(__uint_as_float(u.w << 16),         qv[6], s);
    s = fmaf(__uint_as_float(u.w & 0xffff0000u), qv[7], s);
    return s;
}
__device__ __forceinline__ void pv8_bf(uint4 u, float p, float* acc) {
    acc[0] = fmaf(p, __uint_as_float(u.x << 16),         acc[0]);
    acc[1] = fmaf(p, __uint_as_float(u.x & 0xffff0000u), acc[1]);
    acc[2] = fmaf(p, __uint_as_float(u.y << 16),         acc[2]);
    acc[3] = fmaf(p, __uint_as_float(u.y & 0xffff0000u), acc[3]);
    acc[4] = fmaf(p, __uint_as_float(u.z << 16),         acc[4]);
    acc[5] = fmaf(p, __uint_as_float(u.z & 0xffff0000u), acc[5]);
    acc[6] = fmaf(p, __uint_as_float(u.w << 16),         acc[6]);
    acc[7] = fmaf(p, __uint_as_float(u.w & 0xffff0000u), acc[7]);
}

// ---------------- K1: per-sample sum/sumsq (blocks 0-255) + weight->bf16 (blocks 256-447) ----------------
__global__ __launch_bounds__(256) void k_statsprep(const float* __restrict__ x,
                                                   float* __restrict__ stats,
                                                   const float* __restrict__ qkv_w,
                                                   const float* __restrict__ fc1_w,
                                                   const float* __restrict__ fc2_w,
                                                   const float* __restrict__ proj_w,
                                                   unsigned short* __restrict__ wb) {
    int blk = blockIdx.x;
    if (blk >= 256) {           // prep: 192 blocks x 256 = 49152 weights
        int i = (blk - 256) * 256 + threadIdx.x;
        if (i < 12288)      wb[i] = f2bf(qkv_w[i]);
        else if (i < 28672) wb[i] = f2bf(fc1_w[i - 12288]);
        else if (i < 45056) wb[i] = f2bf(fc2_w[i - 28672]);
        else                wb[i] = f2bf(proj_w[i - 45056]);
        return;
    }
    int n = blk >> 5, chunk = blk & 31;
    const float4* p4 = (const float4*)(x + n * PER_SAMPLE + chunk * 8192);
    int t = threadIdx.x;
    float s1 = 0.f, s2 = 0.f;
#pragma unroll
    for (int i = 0; i < 8; i++) {
        float4 v = p4[t + i * 256];
        s1 += v.x + v.y + v.z + v.w;
        s2 += v.x * v.x + v.y * v.y + v.z * v.z + v.w * v.w;
    }
#pragma unroll
    for (int off = 1; off < 64; off <<= 1) {
        s1 += __shfl_xor(s1, off);
        s2 += __shfl_xor(s2, off);
    }
    __shared__ float r1[4], r2[4];
    int lane = t & 63, wv = t >> 6;
    if (lane == 0) { r1[wv] = s1; r2[wv] = s2; }
    __syncthreads();
    if (t == 0) {
        atomicAdd(&stats[n * 2 + 0], r1[0] + r1[1] + r1[2] + r1[3]);
        atomicAdd(&stats[n * 2 + 1], r2[0] + r2[1] + r2[2] + r2[3]);
    }
}

// ---------------- K2: GN + QKV MFMA, block = 32 tokens (half-row), XCD-banded ----------------
__global__ __launch_bounds__(256) void k_qkv(const float* __restrict__ x,
                                             const float* __restrict__ stats,
                                             const float* __restrict__ gn_w,
                                             const float* __restrict__ gn_b,
                                             const unsigned short* __restrict__ qkv_wb,
                                             const float* __restrict__ qkv_b,
                                             uint4* __restrict__ qb8,
                                             uint4* __restrict__ kvb8) {
    __shared__ __attribute__((aligned(16))) short fragA[2 * 2 * 64 * 8];  // 4 KB (M=32 A-frags)
    __shared__ float obuf[4][16 * 33];                                    // 8.25 KB per-wave transpose
    int xcd = blockIdx.x & 7, idx = blockIdx.x >> 3;
    int half = idx & 1;
    int h = xcd * 8 + ((idx >> 1) & 7);
    int n = idx >> 4;
    int t = threadIdx.x, lane = t & 63;
    int g = __builtin_amdgcn_readfirstlane(t >> 6);
    int s0 = n * 4096 + h * 64 + half * 32;
    int nh = lane & 15, qd = lane >> 4;

    float mu = stats[2 * n] * (1.f / (float)PER_SAMPLE);
    float var = stats[2 * n + 1] * (1.f / (float)PER_SAMPLE) - mu * mu;
    float rstd = rsqrtf(var + EPS);

    // stage A: thread owns 8 channels (cbq*8..+7) of token tok32
    {
        int tok32 = t & 31, cbq = t >> 5;
        const float* xp = x + n * PER_SAMPLE + h * 64 + half * 32 + tok32;
        float v[8];
#pragma unroll
        for (int i = 0; i < 8; i++) {
            int c = cbq * 8 + i;
            v[i] = (xp[(size_t)c * SPATIAL] - mu) * rstd * gn_w[c] + gn_b[c];
        }
        int kf = cbq >> 2, qsel = cbq & 3;
        uint4 p;
        p.x = pack2(v[0], v[1]);
        p.y = pack2(v[2], v[3]);
        p.z = pack2(v[4], v[5]);
        p.w = pack2(v[6], v[7]);
        *(uint4*)&fragA[(((tok32 >> 4) * 2 + kf) * 64 + (tok32 & 15) + (qsel << 4)) * 8] = p;
    }
    __syncthreads();

    short8 af[4];
#pragma unroll
    for (int mt = 0; mt < 2; mt++)
#pragma unroll
        for (int kf = 0; kf < 2; kf++)
            af[mt * 2 + kf] = *(const short8*)&fragA[((mt * 2 + kf) * 64 + lane) * 8];

    for (int nt = 0; nt < 3; nt++) {
        int n0 = g * 48 + nt * 16;
        const unsigned short* wp = qkv_wb + (size_t)(n0 + nh) * 64 + qd * 8;
        short8 b0 = *(const short8*)(wp);
        short8 b1 = *(const short8*)(wp + 32);
        float bias = qkv_b[n0 + nh];
        bool isq = (n0 < 64);
#pragma unroll
        for (int mt = 0; mt < 2; mt++) {
            f32x4 d = {0.f, 0.f, 0.f, 0.f};
            d = __builtin_amdgcn_mfma_f32_16x16x32_bf16(af[mt * 2 + 0], b0, d, 0, 0, 0);
            d = __builtin_amdgcn_mfma_f32_16x16x32_bf16(af[mt * 2 + 1], b1, d, 0, 0, 0);
#pragma unroll
            for (int r = 0; r < 4; r++) {
                float vv = d[r] + bias;
                if (isq) vv *= QSCALE;
                obuf[g][nh * 33 + mt * 16 + qd * 4 + r] = vv;
            }
        }
        __builtin_amdgcn_wave_barrier();
        {
            int tok = lane & 31, u = lane >> 5;
            uint4 p;
            p.x = pack2(obuf[g][(u * 8 + 0) * 33 + tok], obuf[g][(u * 8 + 1) * 33 + tok]);
            p.y = pack2(obuf[g][(u * 8 + 2) * 33 + tok], obuf[g][(u * 8 + 3) * 33 + tok]);
            p.z = pack2(obuf[g][(u * 8 + 4) * 33 + tok], obuf[g][(u * 8 + 5) * 33 + tok]);
            p.w = pack2(obuf[g][(u * 8 + 6) * 33 + tok], obuf[g][(u * 8 + 7) * 33 + tok]);
            int row = (n0 >> 3) + u;
            if (n0 < 64) qb8[(size_t)row * NTOK + s0 + tok] = p;        // q rows 0..7
            else         kvb8[(size_t)(row - 8) * NTOK + s0 + tok] = p;  // k 0..7, v 8..15
        }
        __builtin_amdgcn_wave_barrier();
    }
}

// ---------------- K3: attention + proj + LN + MLP, fused; block = 4x8 tile, LDS-staged K/V ----------------
// 1024 blocks x 256 threads (4 waves). The 10x14-token K/V window (16 ch8-rows) is staged
// into LDS once (coalesced, 9 iters/thread); the 98 gather accesses become ds_read_b128.
// LDS: fragA 4 KB persistent + union{ kvL 36 KB (attention) | obuf+red+lhA 27 KB (MLP) } = 40960 B
// -> 4 blocks/CU at 160 KB LDS.
__global__ __launch_bounds__(256, 4) void k_fused(const uint4* __restrict__ qb8,
                                               const uint4* __restrict__ kvb8,
                                               const float* __restrict__ rpb,
                                               const unsigned short* __restrict__ proj_wb,
                                               const float* __restrict__ proj_b,
                                               const float* __restrict__ x,
                                               const float* __restrict__ ln_w,
                                               const float* __restrict__ ln_b,
                                               const unsigned short* __restrict__ fc1_wb,
                                               const float* __restrict__ fc1_b,
                                               const unsigned short* __restrict__ fc2_wb,
                                               const float* __restrict__ fc2_b,
                                               float* __restrict__ out) {
    __shared__ __attribute__((aligned(16))) char smem[40960];
    short* fragA = (short*)smem;                                   // 4096 B, persistent
    uint4* kvL   = (uint4*)(smem + 4096);                          // 16*144*16 = 36864 B (attention)
    float (*obuf)[16 * 33] = (float(*)[16 * 33])(smem + 4096);     // 8448 B  (MLP, after kvL dead)
    float* red1 = (float*)(smem + 12544);                          // 1024 B
    float* red2 = (float*)(smem + 13568);                          // 1024 B
    short* lhA  = (short*)(smem + 14592);                          // 16384 B (ends 30976)

    int xcd = blockIdx.x & 7, idx = blockIdx.x >> 3;
    int tr = idx & 1;                   // tile-row within the XCD's 8-row band
    int tc = (idx >> 1) & 7;            // tile-col
    int n = idx >> 4;
    int h0 = xcd * 8 + tr * 4, c0 = tc * 8;
    int t = threadIdx.x, lane = t & 63;
    int g = __builtin_amdgcn_readfirstlane(t >> 6);   // head / wave
    int w2 = lane & 31;                 // token id within tile
    int dh = lane >> 5;                 // dim-half (8 channels each)
    int r = w2 >> 3, cseg = w2 & 7;
    int h = h0 + r, w = c0 + cseg;      // spatial position (per-lane)
    int tok = n * 4096 + h * 64 + w;
    int cb = 2 * g + dh;                // 8-channel block id within 64 channels

    int wr0 = max(h0 - 3, 0);           // window origin (10x14 slab, clamped duplicates at edges)
    int wc0 = max(c0 - 3, 0);

    // prefetch x residual + q (independent of staging)
    const float* xr = x + n * PER_SAMPLE + h * 64 + w;
    float xres[8];
#pragma unroll
    for (int i = 0; i < 8; i++)
        xres[i] = xr[(size_t)(cb * 8 + i) * SPATIAL];

    float q[8];
    {
        uint4 qa = qb8[(size_t)cb * NTOK + tok];
        q[0] = __uint_as_float(qa.x << 16); q[1] = __uint_as_float(qa.x & 0xffff0000u);
        q[2] = __uint_as_float(qa.y << 16); q[3] = __uint_as_float(qa.y & 0xffff0000u);
        q[4] = __uint_as_float(qa.z << 16); q[5] = __uint_as_float(qa.z & 0xffff0000u);
        q[6] = __uint_as_float(qa.w << 16); q[7] = __uint_as_float(qa.w & 0xffff0000u);
    }

    // ---- stage K/V window into LDS: 16 ch8-rows x 140 tokens (10 rows x 14 cols) ----
    {
        int nb = n * 4096;
#pragma unroll
        for (int it = 0; it < 9; it++) {
            int i = it * 256 + t;
            if (i < 2240) {
                int rr = i / 140, rem = i - rr * 140;       // const-divisor magic mul
                int swr = rem / 14, swc = rem - swr * 14;
                int rowg = min(wr0 + swr, 63), colg = min(wc0 + swc, 63);
                kvL[rr * 144 + rem] = kvb8[(size_t)rr * NTOK + nb + rowg * 64 + colg];
            }
        }
    }
    __syncthreads();                                    // staging complete

    // ---- neighborhood attention from LDS, one-pass streaming softmax ----
    int sh = min(max(h - 3, 0), HH - KS);
    int sw = min(max(w - 3, 0), WW - KS);

    float sum = 0.f;
    float acc[8];
#pragma unroll
    for (int i = 0; i < 8; i++) acc[i] = 0.f;

#pragma unroll
    for (int a = 0; a < 7; a++) {
        int wi_a = (sh - wr0 + a) * 14 + (sw - wc0);
        const float* rp = rpb + (g * 13 + (h - sh + 6 - a)) * 13 + (w - sw + 6);
        const uint4* kp = kvL + cb * 144 + wi_a;
        const uint4* vp = kvL + (8 + cb) * 144 + wi_a;
#pragma unroll
        for (int bb = 0; bb < 7; bb++) {
            uint4 kv = kp[bb];
            uint4 vv = vp[bb];
            float dhalf = dot8_bf(kv, q);
            float d = dhalf + __shfl_xor(dhalf, 32);   // combine dim-halves
            d += rp[-bb];
            float e = __expf(d);                        // no-max softmax: logits tiny
            sum += e;
            pv8_bf(vv, e, acc);
        }
    }
    float rs = 1.f / sum;

    // stage attn-out (x rs) as bf16 A-frags (M=32, K=64): m=w2, k=cb*8+i
    {
        int kf = cb >> 2, qsel = cb & 3;
        uint4 p;
        p.x = pack2(acc[0] * rs, acc[1] * rs);
        p.y = pack2(acc[2] * rs, acc[3] * rs);
        p.z = pack2(acc[4] * rs, acc[5] * rs);
        p.w = pack2(acc[6] * rs, acc[7] * rs);
        *(uint4*)&fragA[(((w2 >> 4) * 2 + kf) * 64 + (w2 & 15) + (qsel << 4)) * 8] = p;
    }
    __syncthreads();                                    // B1: attention done, kvL dead -> obuf region live

    int nh = lane & 15, qd = lane >> 4;
    float yreg[8];                                      // y = proj(attn)+bias+x
    // ---- proj MFMA (M=32, N=16/wave, K=64) ----
    {
        short8 af[4];
#pragma unroll
        for (int mt = 0; mt < 2; mt++)
#pragma unroll
            for (int kf = 0; kf < 2; kf++)
                af[mt * 2 + kf] = *(const short8*)&fragA[((mt * 2 + kf) * 64 + lane) * 8];

        int n0 = g * 16;
        const unsigned short* wp = proj_wb + (size_t)(n0 + nh) * 64 + qd * 8;
        short8 b0 = *(const short8*)(wp);
        short8 b1 = *(const short8*)(wp + 32);
        float bias = proj_b[n0 + nh];
#pragma unroll
        for (int mt = 0; mt < 2; mt++) {
            f32x4 d = {0.f, 0.f, 0.f, 0.f};
            d = __builtin_amdgcn_mfma_f32_16x16x32_bf16(af[mt * 2 + 0], b0, d, 0, 0, 0);
            d = __builtin_amdgcn_mfma_f32_16x16x32_bf16(af[mt * 2 + 1], b1, d, 0, 0, 0);
#pragma unroll
            for (int r2 = 0; r2 < 4; r2++)
                obuf[g][nh * 33 + mt * 16 + qd * 4 + r2] = d[r2] + bias;
        }
        __builtin_amdgcn_wave_barrier();
#pragma unroll
        for (int i = 0; i < 8; i++)
            yreg[i] = obuf[g][(dh * 8 + i) * 33 + w2] + xres[i];
    }

    // ---- LN (8 threads per token) -> fragA (yn A-frags) ----
    {
        float s1 = 0.f, s2 = 0.f;
#pragma unroll
        for (int i = 0; i < 8; i++) { s1 += yreg[i]; s2 += yreg[i] * yreg[i]; }
        red1[t] = s1;
        red2[t] = s2;
        __syncthreads();                                // B2 (also orders fragA reuse)
        float m1 = 0.f, m2 = 0.f;
#pragma unroll
        for (int u = 0; u < 8; u++) { m1 += red1[u * 32 + w2]; m2 += red2[u * 32 + w2]; }
        float mu = m1 * (1.f / 64.f);
        float rstd = rsqrtf(m2 * (1.f / 64.f) - mu * mu + EPS);
        float v[8];
#pragma unroll
        for (int i = 0; i < 8; i++) {
            int c = cb * 8 + i;
            v[i] = (yreg[i] - mu) * rstd * ln_w[c] + ln_b[c];
        }
        int kf = cb >> 2, qsel = cb & 3;
        uint4 p;
        p.x = pack2(v[0], v[1]);
        p.y = pack2(v[2], v[3]);
        p.z = pack2(v[4], v[5]);
        p.w = pack2(v[6], v[7]);
        *(uint4*)&fragA[(((w2 >> 4) * 2 + kf) * 64 + (w2 & 15) + (qsel << 4)) * 8] = p;
    }
    __syncthreads();                                    // B3

    // ---- fc1 + GELU -> lhA (fc2 A-frag layout, M=32, K=256) ----
    {
        short8 yf[4];
#pragma unroll
        for (int mt = 0; mt < 2; mt++)
#pragma unroll
            for (int kf = 0; kf < 2; kf++)
                yf[mt * 2 + kf] = *(const short8*)&fragA[((mt * 2 + kf) * 64 + lane) * 8];

#pragma unroll
        for (int nt = 0; nt < 4; nt++) {
            int n0f = g * 64 + nt * 16;
            const unsigned short* wp = fc1_wb + (size_t)(n0f + nh) * 64 + qd * 8;
            short8 b0 = *(const short8*)(wp);
            short8 b1 = *(const short8*)(wp + 32);
            float bias = fc1_b[n0f + nh];
            int j = n0f + nh;
            int kfA = j >> 5, q2 = (j >> 3) & 3, jb = j & 7;
#pragma unroll
            for (int mt = 0; mt < 2; mt++) {
                f32x4 d = {0.f, 0.f, 0.f, 0.f};
                d = __builtin_amdgcn_mfma_f32_16x16x32_bf16(yf[mt * 2 + 0], b0, d, 0, 0, 0);
                d = __builtin_amdgcn_mfma_f32_16x16x32_bf16(yf[mt * 2 + 1], b1, d, 0, 0, 0);
#pragma unroll
                for (int r2 = 0; r2 < 4; r2++) {
                    float hv = d[r2] + bias;
                    hv = 0.5f * hv * (1.f + erff(hv * 0.70710678118654752f));
                    lhA[((mt * 8 + kfA) * 64 + (qd * 4 + r2) + (q2 << 4)) * 8 + jb] = (short)f2bf(hv);
                }
            }
        }
    }
    __syncthreads();                                    // B4

    // ---- fc2 (M=32, N=16/wave, K=256 in one pass) ----
    f32x4 acc2[2];
    acc2[0] = (f32x4){0.f, 0.f, 0.f, 0.f};
    acc2[1] = (f32x4){0.f, 0.f, 0.f, 0.f};
#pragma unroll
    for (int kfA = 0; kfA < 8; kfA++) {
        const unsigned short* wp = fc2_wb + (size_t)(g * 16 + nh) * 256 + kfA * 32 + qd * 8;
        short8 bb = *(const short8*)(wp);
#pragma unroll
        for (int mt = 0; mt < 2; mt++) {
            short8 a = *(const short8*)&lhA[((mt * 8 + kfA) * 64 + lane) * 8];
            acc2[mt] = __builtin_amdgcn_mfma_f32_16x16x32_bf16(a, bb, acc2[mt], 0, 0, 0);
        }
    }
    // ---- epilogue: per-wave transpose, + fc2_b + y residual, NCHW store ----
#pragma unroll
    for (int mt = 0; mt < 2; mt++)
#pragma unroll
        for (int r2 = 0; r2 < 4; r2++)
            obuf[g][nh * 33 + mt * 16 + qd * 4 + r2] = acc2[mt][r2];
    __builtin_amdgcn_wave_barrier();
    float* op = out + (size_t)n * PER_SAMPLE + h * 64 + w;
#pragma unroll
    for (int i = 0; i < 8; i++) {
        int c = cb * 8 + i;
        op[(size_t)c * SPATIAL] = obuf[g][(dh * 8 + i) * 33 + w2] + fc2_b[c] + yreg[i];
    }
}

extern "C" void kernel_launch(void* const* d_in, const int* in_sizes, int n_in,
                              void* d_out, int out_size, void* d_ws, size_t ws_size,
                              hipStream_t stream) {
    const float* x      = (const float*)d_in[0];
    const float* gn_w   = (const float*)d_in[1];
    const float* gn_b   = (const float*)d_in[2];
    const float* qkv_w  = (const float*)d_in[3];
    const float* qkv_b  = (const float*)d_in[4];
    const float* rpb    = (const float*)d_in[5];
    const float* proj_w = (const float*)d_in[6];
    const float* proj_b = (const float*)d_in[7];
    const float* ln_w   = (const float*)d_in[8];
    const float* ln_b   = (const float*)d_in[9];
    const float* fc1_w  = (const float*)d_in[10];
    const float* fc1_b  = (const float*)d_in[11];
    const float* fc2_w  = (const float*)d_in[12];
    const float* fc2_b  = (const float*)d_in[13];
    float* out = (float*)d_out;

    float* ws    = (float*)d_ws;
    float* stats = ws;                                      // 64 floats
    uint4* qb8   = (uint4*)(ws + 64);                       // 8  * NTOK uint4 = 4.2 MB
    uint4* kvb8  = qb8 + (size_t)8 * NTOK;                  // 16 * NTOK uint4 = 8.4 MB
    unsigned short* wb = (unsigned short*)(kvb8 + (size_t)16 * NTOK);  // 49152 bf16
    unsigned short* qkv_wb  = wb;
    unsigned short* fc1_wb  = wb + 12288;
    unsigned short* fc2_wb  = wb + 28672;
    unsigned short* proj_wb = wb + 45056;

    hipMemsetAsync(stats, 0, 64, stream);
    k_statsprep<<<448, 256, 0, stream>>>(x, stats, qkv_w, fc1_w, fc2_w, proj_w, wb);
    k_qkv      <<<1024, 256, 0, stream>>>(x, stats, gn_w, gn_b, qkv_wb, qkv_b, qb8, kvb8);
    k_fused    <<<1024, 256, 0, stream>>>(qb8, kvb8, rpb, proj_wb, proj_b, x,
                                          ln_w, ln_b, fc1_wb, fc1_b, fc2_wb, fc2_b, out);
}